// Round 2
// baseline (18375.749 us; speedup 1.0000x reference)
//
#include <hip/hip_runtime.h>

// Problem constants
#define Bz 64
#define Nz 64
#define Tz 60
#define Dz 4
#define Hz 64
#define ETz 4
#define Ez 4032   // Nz*(Nz-1)

__device__ __forceinline__ float ftanh(float x) {
    float e = __expf(2.0f * x);
    return 1.0f - 2.0f * __builtin_amdgcn_rcpf(e + 1.0f);
}
__device__ __forceinline__ float fsig(float x) {
    return __builtin_amdgcn_rcpf(1.0f + __expf(-x));
}

// ---------------------------------------------------------------------------
// Setup: clinical MLPs -> hidden (initial h) and cln_msg.  One block per batch.
// ---------------------------------------------------------------------------
__global__ __launch_bounds__(128) void k_clinical(
    const float* __restrict__ clin,
    const float* __restrict__ hw1, const float* __restrict__ hb1,
    const float* __restrict__ hw2, const float* __restrict__ hb2,
    const float* __restrict__ hw3, const float* __restrict__ hb3,
    const float* __restrict__ mw1, const float* __restrict__ mb1,
    const float* __restrict__ mw2, const float* __restrict__ mb2,
    const float* __restrict__ mw3, const float* __restrict__ mb3,
    float* __restrict__ hidden, float* __restrict__ clnmsg)
{
    int b = blockIdx.x, tid = threadIdx.x;
    __shared__ float sc[16], s1[64], s2[128];
    if (tid < 16) sc[tid] = clin[b * 16 + tid];
    __syncthreads();
    for (int head = 0; head < 2; ++head) {
        const float* w1 = head ? mw1 : hw1; const float* b1 = head ? mb1 : hb1;
        const float* w2 = head ? mw2 : hw2; const float* b2 = head ? mb2 : hb2;
        const float* w3 = head ? mw3 : hw3; const float* b3 = head ? mb3 : hb3;
        float* outp = head ? clnmsg : hidden;
        if (tid < 64) {
            float a = b1[tid];
            #pragma unroll
            for (int c = 0; c < 16; ++c) a = fmaf(sc[c], w1[c * 64 + tid], a);
            s1[tid] = fmaxf(a, 0.f);
        }
        __syncthreads();
        {
            float a = b2[tid];
            #pragma unroll 8
            for (int c = 0; c < 64; ++c) a = fmaf(s1[c], w2[c * 128 + tid], a);
            s2[tid] = fmaxf(a, 0.f);
        }
        __syncthreads();
        for (int j = tid; j < 4096; j += 128) {
            float a = b3[j];
            #pragma unroll 8
            for (int c = 0; c < 128; ++c) a = fmaf(s2[c], w3[c * 4096 + j], a);
            outp[b * 4096 + j] = a;
        }
        __syncthreads();
    }
}

// ---------------------------------------------------------------------------
// Setup: transpose msg_w2 [t][k][h] -> W2T [t][h][k]
// ---------------------------------------------------------------------------
__global__ __launch_bounds__(256) void k_wprep(const float* __restrict__ w2,
                                               float* __restrict__ w2t)
{
    int i = blockIdx.x * 256 + threadIdx.x;   // 16384 elements
    int t = i >> 12, k = (i >> 6) & 63, hh = i & 63;
    w2t[t * 4096 + hh * 64 + k] = w2[i];
}

// ---------------------------------------------------------------------------
// Setup: x0 = data[:,:,0,:] -> xbuf and out[:,:,0,:]
// ---------------------------------------------------------------------------
__global__ __launch_bounds__(256) void k_init(const float* __restrict__ data,
                                              float* __restrict__ xbuf,
                                              float* __restrict__ out)
{
    int i = blockIdx.x * 256 + threadIdx.x;   // Bz*Nz*Dz = 16384 exactly
    int bn = i >> 2, d = i & 3;
    float v = data[bn * (Tz * Dz) + d];       // data[b][n][0][d]
    xbuf[i] = v;
    out[bn * (Tz * Dz) + d] = v;
}

// ---------------------------------------------------------------------------
// Projection: Hrb[b][n][t][k] = h[b,n]@W1r[t] + b1[t]   (bias folded here)
//             Hs [b][t][k][n] = h[b,n]@W1s[t]           (transposed layout)
// One wave per (b,n); lane = output channel k.
// ---------------------------------------------------------------------------
__global__ __launch_bounds__(64) void k_proj(
    const float* __restrict__ h, const float* __restrict__ w1,
    const float* __restrict__ b1,
    float* __restrict__ Hrb, float* __restrict__ Hs)
{
    int blk = blockIdx.x;
    int b = blk >> 6, n = blk & 63;
    int l = threadIdx.x;
    __shared__ float sh[64];
    sh[l] = h[blk * 64 + l];
    __syncthreads();
    #pragma unroll 1
    for (int t = 0; t < 4; ++t) {
        const float* w = w1 + t * 8192;       // [128][64] slice
        float ar = b1[t * 64 + l], as = 0.f;
        #pragma unroll 8
        for (int c = 0; c < 64; ++c) {
            float hv = sh[c];
            ar = fmaf(hv, w[c * 64 + l], ar);
            as = fmaf(hv, w[(c + 64) * 64 + l], as);
        }
        Hrb[(blk * 4 + t) * 64 + l] = ar;
        Hs[((b * 4 + t) * 64 + l) * 64 + n] = as;
    }
}

// ---------------------------------------------------------------------------
// Edge/message kernel.  One wave per (b, receiver). lane = edge (63 valid).
// Computes agg_raw[b][recv][:] = (1/16) * sum_edges sum_t tanh-MLP msgs.
// ---------------------------------------------------------------------------
__global__ __launch_bounds__(64) void k_edge(
    const float* __restrict__ Hrb, const float* __restrict__ Hs,
    const float* __restrict__ rel_type, const float* __restrict__ b2,
    const float* __restrict__ W2T, float* __restrict__ agg)
{
    int blk = blockIdx.x;
    int b = blk >> 6, rv = blk & 63;
    int l = threadIdx.x;
    __shared__ float sAm[64 * 65];
    #pragma unroll
    for (int k = 0; k < 64; ++k) sAm[l * 65 + k] = 0.f;

    // sender index for edge l of receiver rv; lane 63 is a dummy (weight 0)
    int snd = (l < 63) ? (l + (l >= rv ? 1 : 0)) : rv;
    float rt0 = 0.f, rt1 = 0.f, rt2 = 0.f, rt3 = 0.f;
    if (l < 63) {
        const float* rp = rel_type + (b * Ez + rv * 63 + l) * 4;
        rt0 = rp[0]; rt1 = rp[1]; rt2 = rp[2]; rt3 = rp[3];
    }
    const float* HrP = Hrb + blk * 256;           // [4][64], wave-uniform
    const float* HsP = Hs + b * 16384 + snd;      // per-lane column
    __syncthreads();

    #pragma unroll 1
    for (int t = 0; t < 4; ++t) {
        float rtt = (t == 0) ? rt0 : (t == 1) ? rt1 : (t == 2) ? rt2 : rt3;
        float z1[64];
        const float* hr  = HrP + t * 64;
        const float* hsp = HsP + t * 4096;
        #pragma unroll
        for (int k = 0; k < 64; ++k)
            z1[k] = ftanh(hr[k] + hsp[k * 64]);

        const float* wt = W2T + t * 4096;
        const float* bb = b2 + t * 64;
        #pragma unroll 2
        for (int h = 0; h < 64; ++h) {
            const float* wr = wt + h * 64;
            float a0 = 0.f, a1 = 0.f, a2 = 0.f, a3 = 0.f;
            #pragma unroll
            for (int k = 0; k < 64; k += 4) {
                a0 = fmaf(z1[k + 0], wr[k + 0], a0);
                a1 = fmaf(z1[k + 1], wr[k + 1], a1);
                a2 = fmaf(z1[k + 2], wr[k + 2], a2);
                a3 = fmaf(z1[k + 3], wr[k + 3], a3);
            }
            float m2 = ftanh((a0 + a1) + (a2 + a3) + bb[h]);
            sAm[h * 65 + l] += m2 * rtt;
        }
    }
    __syncthreads();
    float s = 0.f;
    #pragma unroll
    for (int k = 0; k < 64; ++k) s += sAm[l * 65 + k];
    agg[blk * 64 + l] = s * 0.0625f;              // /ET(4) and /D(4)
}

// ---------------------------------------------------------------------------
// Node kernel: GRU + output MLP + pred write + next-step projections.
// One wave per (b,n); lane = hidden channel.
// ---------------------------------------------------------------------------
__global__ __launch_bounds__(64) void k_node(
    const float* __restrict__ aggraw, const float* __restrict__ cln,
    float* __restrict__ hbuf, float* __restrict__ xbuf,
    const float* __restrict__ irw, const float* __restrict__ irb,
    const float* __restrict__ izw, const float* __restrict__ izb,
    const float* __restrict__ inw, const float* __restrict__ inb,
    const float* __restrict__ hrw, const float* __restrict__ hrbv,
    const float* __restrict__ hnw, const float* __restrict__ hnbv,
    const float* __restrict__ o1w, const float* __restrict__ o1b,
    const float* __restrict__ o2w, const float* __restrict__ o2b,
    const float* __restrict__ o3w, const float* __restrict__ o3b,
    const float* __restrict__ w1, const float* __restrict__ b1,
    float* __restrict__ Hrb, float* __restrict__ Hs,
    float* __restrict__ out, int tout)
{
    int blk = blockIdx.x;
    int b = blk >> 6, n = blk & 63;
    int l = threadIdx.x;
    __shared__ float sA[64], sH[64], sP[64];

    float a = aggraw[blk * 64 + l] + cln[blk * 64 + l];
    sA[l] = a;
    float h_old = hbuf[blk * 64 + l];
    float x0 = xbuf[blk * 4 + 0], x1 = xbuf[blk * 4 + 1];
    float x2 = xbuf[blk * 4 + 2], x3 = xbuf[blk * 4 + 3];
    __syncthreads();

    float hra = hrbv[l], hna = hnbv[l];
    #pragma unroll 8
    for (int k = 0; k < 64; ++k) {
        float av = sA[k];
        hra = fmaf(av, hrw[k * 64 + l], hra);
        hna = fmaf(av, hnw[k * 64 + l], hna);
    }
    float xr = irb[l]; float xz = izb[l]; float xn = inb[l];
    xr = fmaf(x0, irw[l], xr); xr = fmaf(x1, irw[64 + l], xr);
    xr = fmaf(x2, irw[128 + l], xr); xr = fmaf(x3, irw[192 + l], xr);
    xz = fmaf(x0, izw[l], xz); xz = fmaf(x1, izw[64 + l], xz);
    xz = fmaf(x2, izw[128 + l], xz); xz = fmaf(x3, izw[192 + l], xz);
    xn = fmaf(x0, inw[l], xn); xn = fmaf(x1, inw[64 + l], xn);
    xn = fmaf(x2, inw[128 + l], xn); xn = fmaf(x3, inw[192 + l], xn);

    float r = fsig(xr + hra);
    float z = fsig(xz + hra);
    float nn = ftanh(xn + r * hna);
    float hnew = (1.f - z) * nn + z * h_old;
    hbuf[blk * 64 + l] = hnew;
    sH[l] = hnew;
    __syncthreads();

    float p = o1b[l];
    #pragma unroll 8
    for (int k = 0; k < 64; ++k) p = fmaf(sH[k], o1w[k * 64 + l], p);
    p = fmaxf(p, 0.f);
    sP[l] = p;
    __syncthreads();
    float q = o2b[l];
    #pragma unroll 8
    for (int k = 0; k < 64; ++k) q = fmaf(sP[k], o2w[k * 64 + l], q);
    q = fmaxf(q, 0.f);
    __syncthreads();
    sP[l] = q;
    __syncthreads();
    if (l < 4) {
        float xv = (l == 0) ? x0 : (l == 1) ? x1 : (l == 2) ? x2 : x3;
        float pr = xv + o3b[l];
        #pragma unroll 8
        for (int k = 0; k < 64; ++k) pr = fmaf(sP[k], o3w[k * 4 + l], pr);
        out[(blk * Tz + tout) * 4 + l] = pr;
        xbuf[blk * 4 + l] = pr;
    }

    // projections for next step (bias b1 folded into Hrb)
    #pragma unroll 1
    for (int t = 0; t < 4; ++t) {
        const float* w = w1 + t * 8192;
        float ar = b1[t * 64 + l], as = 0.f;
        #pragma unroll 8
        for (int c = 0; c < 64; ++c) {
            float hv = sH[c];
            ar = fmaf(hv, w[c * 64 + l], ar);
            as = fmaf(hv, w[(c + 64) * 64 + l], as);
        }
        Hrb[(blk * 4 + t) * 64 + l] = ar;
        Hs[((b * 4 + t) * 64 + l) * 64 + n] = as;
    }
}

// ---------------------------------------------------------------------------
extern "C" void kernel_launch(void* const* d_in, const int* in_sizes, int n_in,
                              void* d_out, int out_size, void* d_ws, size_t ws_size,
                              hipStream_t stream)
{
    const float* data     = (const float*)d_in[0];
    const float* rel_type = (const float*)d_in[1];
    // d_in[2] rel_rec, d_in[3] rel_send: structure hard-coded (row-major where(~eye))
    const float* clinical = (const float*)d_in[4];
    const float* msg_w1 = (const float*)d_in[5];
    const float* msg_b1 = (const float*)d_in[6];
    const float* msg_w2 = (const float*)d_in[7];
    const float* msg_b2 = (const float*)d_in[8];
    const float* chw1 = (const float*)d_in[9];
    const float* chb1 = (const float*)d_in[10];
    const float* chw2 = (const float*)d_in[11];
    const float* chb2 = (const float*)d_in[12];
    const float* chw3 = (const float*)d_in[13];
    const float* chb3 = (const float*)d_in[14];
    const float* cmw1 = (const float*)d_in[15];
    const float* cmb1 = (const float*)d_in[16];
    const float* cmw2 = (const float*)d_in[17];
    const float* cmb2 = (const float*)d_in[18];
    const float* cmw3 = (const float*)d_in[19];
    const float* cmb3 = (const float*)d_in[20];
    const float* irw = (const float*)d_in[21];
    const float* irb = (const float*)d_in[22];
    const float* izw = (const float*)d_in[23];
    const float* izb = (const float*)d_in[24];
    const float* inw = (const float*)d_in[25];
    const float* inb = (const float*)d_in[26];
    const float* hrw = (const float*)d_in[27];
    const float* hrb = (const float*)d_in[28];
    const float* hnw = (const float*)d_in[29];
    const float* hnb = (const float*)d_in[30];
    const float* o1w = (const float*)d_in[31];
    const float* o1b = (const float*)d_in[32];
    const float* o2w = (const float*)d_in[33];
    const float* o2b = (const float*)d_in[34];
    const float* o3w = (const float*)d_in[35];
    const float* o3b = (const float*)d_in[36];

    float* ws   = (float*)d_ws;
    float* hbuf = ws;                 // B*N*H           = 262144
    float* cln  = ws + 262144;        // B*N*H           = 262144
    float* Hrb  = ws + 524288;        // B*N*ET*H        = 1048576
    float* Hs   = ws + 1572864;       // B*ET*H*N        = 1048576
    float* agg  = ws + 2621440;       // B*N*H           = 262144
    float* xbuf = ws + 2883584;       // B*N*D           = 16384
    float* W2T  = ws + 2899968;       // ET*H*H          = 16384
    float* out  = (float*)d_out;

    k_clinical<<<dim3(Bz), dim3(128), 0, stream>>>(
        clinical, chw1, chb1, chw2, chb2, chw3, chb3,
        cmw1, cmb1, cmw2, cmb2, cmw3, cmb3, hbuf, cln);
    k_wprep<<<dim3(64), dim3(256), 0, stream>>>(msg_w2, W2T);
    k_init<<<dim3(64), dim3(256), 0, stream>>>(data, xbuf, out);
    k_proj<<<dim3(Bz * Nz), dim3(64), 0, stream>>>(hbuf, msg_w1, msg_b1, Hrb, Hs);

    for (int t = 1; t < Tz; ++t) {
        k_edge<<<dim3(Bz * Nz), dim3(64), 0, stream>>>(Hrb, Hs, rel_type, msg_b2, W2T, agg);
        k_node<<<dim3(Bz * Nz), dim3(64), 0, stream>>>(
            agg, cln, hbuf, xbuf,
            irw, irb, izw, izb, inw, inb,
            hrw, hrb, hnw, hnb,
            o1w, o1b, o2w, o2b, o3w, o3b,
            msg_w1, msg_b1, Hrb, Hs, out, t);
    }
}

// Round 3
// 7152.438 us; speedup vs baseline: 2.5692x; 2.5692x over previous
//
#include <hip/hip_runtime.h>

// Problem constants
#define Bz 64
#define Nz 64
#define Tz 60
#define Dz 4
#define Hz 64
#define ETz 4
#define Ez 4032   // Nz*(Nz-1)

typedef _Float16 f16x8 __attribute__((ext_vector_type(8)));
typedef float    f32x4 __attribute__((ext_vector_type(4)));
typedef unsigned int u32;
typedef u32      u32x4 __attribute__((ext_vector_type(4)));

__device__ __forceinline__ float ftanh(float x) {
    float e = __expf(2.0f * x);
    return 1.0f - 2.0f * __builtin_amdgcn_rcpf(e + 1.0f);
}
__device__ __forceinline__ float fsig(float x) {
    return __builtin_amdgcn_rcpf(1.0f + __expf(-x));
}

// split fp32 into f16 hi + f16 lo*4096, packed u32 = hi | lo<<16
__device__ __forceinline__ u32 pack_split(float z) {
    _Float16 h = (_Float16)z;
    float hf = (float)h;
    _Float16 l = (_Float16)((z - hf) * 4096.0f);
    u32 hb = (u32)__builtin_bit_cast(unsigned short, h);
    u32 lb = (u32)__builtin_bit_cast(unsigned short, l);
    return hb | (lb << 16);
}
__device__ __forceinline__ u32 lo16pair(u32 a, u32 b) { return (a & 0xFFFFu) | (b << 16); }
__device__ __forceinline__ u32 hi16pair(u32 a, u32 b) { return (a >> 16) | (b & 0xFFFF0000u); }

__device__ __forceinline__ f16x8 mk_hi(u32x4 q0, u32x4 q1) {
    u32x4 r; r.x = lo16pair(q0.x, q0.y); r.y = lo16pair(q0.z, q0.w);
    r.z = lo16pair(q1.x, q1.y); r.w = lo16pair(q1.z, q1.w);
    return __builtin_bit_cast(f16x8, r);
}
__device__ __forceinline__ f16x8 mk_lo(u32x4 q0, u32x4 q1) {
    u32x4 r; r.x = hi16pair(q0.x, q0.y); r.y = hi16pair(q0.z, q0.w);
    r.z = hi16pair(q1.x, q1.y); r.w = hi16pair(q1.z, q1.w);
    return __builtin_bit_cast(f16x8, r);
}

// ---------------------------------------------------------------------------
// Setup: clinical MLPs -> hidden (initial h) and cln_msg.
// Grid 512 = 64 b x 8 j-blocks (512 outputs each) for parallelism.
// ---------------------------------------------------------------------------
__global__ __launch_bounds__(128) void k_clinical(
    const float* __restrict__ clin,
    const float* __restrict__ hw1, const float* __restrict__ hb1,
    const float* __restrict__ hw2, const float* __restrict__ hb2,
    const float* __restrict__ hw3, const float* __restrict__ hb3,
    const float* __restrict__ mw1, const float* __restrict__ mb1,
    const float* __restrict__ mw2, const float* __restrict__ mb2,
    const float* __restrict__ mw3, const float* __restrict__ mb3,
    float* __restrict__ hidden, float* __restrict__ clnmsg)
{
    int b = blockIdx.x >> 3, jb = blockIdx.x & 7, tid = threadIdx.x;
    __shared__ float sc[16], s1[64], s2[128];
    if (tid < 16) sc[tid] = clin[b * 16 + tid];
    __syncthreads();
    for (int head = 0; head < 2; ++head) {
        const float* w1 = head ? mw1 : hw1; const float* b1 = head ? mb1 : hb1;
        const float* w2 = head ? mw2 : hw2; const float* b2 = head ? mb2 : hb2;
        const float* w3 = head ? mw3 : hw3; const float* b3 = head ? mb3 : hb3;
        float* outp = head ? clnmsg : hidden;
        if (tid < 64) {
            float a = b1[tid];
            #pragma unroll
            for (int c = 0; c < 16; ++c) a = fmaf(sc[c], w1[c * 64 + tid], a);
            s1[tid] = fmaxf(a, 0.f);
        }
        __syncthreads();
        {
            float a = b2[tid];
            #pragma unroll 8
            for (int c = 0; c < 64; ++c) a = fmaf(s1[c], w2[c * 128 + tid], a);
            s2[tid] = fmaxf(a, 0.f);
        }
        __syncthreads();
        for (int j = jb * 512 + tid; j < jb * 512 + 512; j += 128) {
            float a = b3[j];
            #pragma unroll 8
            for (int c = 0; c < 128; ++c) a = fmaf(s2[c], w3[c * 4096 + j], a);
            outp[b * 4096 + j] = a;
        }
        __syncthreads();
    }
}

// ---------------------------------------------------------------------------
// Setup: msg_w2 [t][k][g] -> fragment-ready split-f16 layout
// Wf[((t*8 + n*2 + kt)*64 + L)*8 + j] packs B[k][g] for
// k = kt*32 + (L>>4)*8 + j, g = n*16 + (L&15).
// ---------------------------------------------------------------------------
__global__ __launch_bounds__(256) void k_wprep(const float* __restrict__ w2,
                                               u32* __restrict__ Wf)
{
    int id = blockIdx.x * 256 + threadIdx.x;   // 16384
    int j = id & 7, L = (id >> 3) & 63, r = id >> 9;
    int kt = r & 1, n = (r >> 1) & 3, t = r >> 3;
    int k = kt * 32 + ((L >> 4) << 3) + j;
    int g = n * 16 + (L & 15);
    float w = w2[(t * 64 + k) * 64 + g];
    Wf[id] = pack_split(w);
}

// ---------------------------------------------------------------------------
// Setup: x0 = data[:,:,0,:] -> xbuf and out[:,:,0,:]
// ---------------------------------------------------------------------------
__global__ __launch_bounds__(256) void k_init(const float* __restrict__ data,
                                              float* __restrict__ xbuf,
                                              float* __restrict__ out)
{
    int i = blockIdx.x * 256 + threadIdx.x;   // 16384
    int bn = i >> 2, d = i & 3;
    float v = data[bn * (Tz * Dz) + d];
    xbuf[i] = v;
    out[bn * (Tz * Dz) + d] = v;
}

// ---------------------------------------------------------------------------
// Projection: Hrb[blk][t][k] = h@W1r[t] + b1[t];  Hs[b][t][k][n] = h@W1s[t]
// ---------------------------------------------------------------------------
__global__ __launch_bounds__(64) void k_proj(
    const float* __restrict__ h, const float* __restrict__ w1,
    const float* __restrict__ b1,
    float* __restrict__ Hrb, float* __restrict__ Hs)
{
    int blk = blockIdx.x;
    int b = blk >> 6, n = blk & 63;
    int l = threadIdx.x;
    __shared__ float sh[64];
    sh[l] = h[blk * 64 + l];
    __syncthreads();
    #pragma unroll 1
    for (int t = 0; t < 4; ++t) {
        const float* w = w1 + t * 8192;
        float ar = b1[t * 64 + l], as = 0.f;
        #pragma unroll 8
        for (int c = 0; c < 64; ++c) {
            float hv = sh[c];
            ar = fmaf(hv, w[c * 64 + l], ar);
            as = fmaf(hv, w[(c + 64) * 64 + l], as);
        }
        Hrb[(blk * 4 + t) * 64 + l] = ar;
        Hs[((b * 4 + t) * 64 + l) * 64 + n] = as;
    }
}

// ---------------------------------------------------------------------------
// Edge/message kernel, MFMA split-f16 version.
// One wave per (b, rv). M=64 edges (63 + pad), N=64 channels, K=64, x4 types.
// 16x16x32 f16 MFMA; A layout: lane holds A[L%16][8*(L/16)+j];
// B: B[8*(L/16)+j][L%16]; C/D: D[(L>>4)*4+r][L&15] (verified layout).
// ---------------------------------------------------------------------------
__global__ __launch_bounds__(64) void k_edge(
    const float* __restrict__ Hrb, const float* __restrict__ Hs,
    const float* __restrict__ rel_type, const float* __restrict__ b2,
    const u32* __restrict__ Wf, float* __restrict__ agg)
{
    int blk = blockIdx.x;
    int b = blk >> 6, rv = blk & 63;
    int L = threadIdx.x;
    __shared__ __align__(16) u32 Za[4096];    // [e][k] packed, 16B-chunk XOR swizzle
    __shared__ __align__(16) float srt[256];  // [t][e] rel_type transposed

    // stage rel_type transposed (pad edge 63 with 0)
    const float* rbase = rel_type + (b * Ez + rv * 63) * 4;
    #pragma unroll
    for (int r = 0; r < 4; ++r) {
        int idx = r * 64 + L;
        float v = (idx < 252) ? rbase[idx] : 0.f;
        srt[(idx & 3) * 64 + (idx >> 2)] = v;
    }

    int snd = (L < 63) ? (L + (L >= rv ? 1 : 0)) : rv;
    int e7 = L & 7;
    float accg0 = 0.f, accg1 = 0.f, accg2 = 0.f, accg3 = 0.f;

    #pragma unroll 1
    for (int t = 0; t < 4; ++t) {
        // ---- z1 = tanh(Hr + Hs_col), lane = edge ----
        const float* hr = Hrb + blk * 256 + t * 64;      // wave-uniform
        const float* hs = Hs + (b * 4 + t) * 4096 + snd; // per-lane column
        float z[64];
        #pragma unroll
        for (int k = 0; k < 64; ++k) z[k] = ftanh(hr[k] + hs[k * 64]);

        // ---- pack split-f16 into LDS (swizzled 16B chunks) ----
        #pragma unroll
        for (int c = 0; c < 16; ++c) {
            u32x4 w;
            w.x = pack_split(z[4 * c + 0]);
            w.y = pack_split(z[4 * c + 1]);
            w.z = pack_split(z[4 * c + 2]);
            w.w = pack_split(z[4 * c + 3]);
            *(u32x4*)&Za[L * 64 + ((c ^ e7) << 2)] = w;
        }

        // ---- load B fragments for this t (precomputed layout) ----
        f16x8 Bh[8], Bl[8];   // index n*2+kt
        #pragma unroll
        for (int nk = 0; nk < 8; ++nk) {
            const u32x4* wp = (const u32x4*)(Wf + ((t * 8 + nk) * 64 + L) * 8);
            u32x4 p0 = wp[0], p1 = wp[1];
            Bh[nk] = mk_hi(p0, p1);
            Bl[nk] = mk_lo(p0, p1);
        }

        float b2n[4];
        #pragma unroll
        for (int n = 0; n < 4; ++n) b2n[n] = b2[t * 64 + n * 16 + (L & 15)];

        // ---- M-tiles ----
        #pragma unroll
        for (int m = 0; m < 4; ++m) {
            int e = m * 16 + (L & 15);               // e&7 == e7
            int c0 = (L >> 4) * 2;
            f16x8 Ah[2], Al[2];
            #pragma unroll
            for (int kt = 0; kt < 2; ++kt) {
                int cA = kt * 8 + c0;
                u32x4 q0 = *(const u32x4*)&Za[e * 64 + ((cA ^ e7) << 2)];
                u32x4 q1 = *(const u32x4*)&Za[e * 64 + (((cA + 1) ^ e7) << 2)];
                Ah[kt] = mk_hi(q0, q1);
                Al[kt] = mk_lo(q0, q1);
            }
            f32x4 rt4 = *(const f32x4*)&srt[t * 64 + m * 16 + ((L >> 4) << 2)];
            #pragma unroll
            for (int n = 0; n < 4; ++n) {
                f32x4 hh = {0.f, 0.f, 0.f, 0.f};
                f32x4 cc = {0.f, 0.f, 0.f, 0.f};
                hh = __builtin_amdgcn_mfma_f32_16x16x32_f16(Ah[0], Bh[n*2+0], hh, 0, 0, 0);
                hh = __builtin_amdgcn_mfma_f32_16x16x32_f16(Ah[1], Bh[n*2+1], hh, 0, 0, 0);
                cc = __builtin_amdgcn_mfma_f32_16x16x32_f16(Ah[0], Bl[n*2+0], cc, 0, 0, 0);
                cc = __builtin_amdgcn_mfma_f32_16x16x32_f16(Al[0], Bh[n*2+0], cc, 0, 0, 0);
                cc = __builtin_amdgcn_mfma_f32_16x16x32_f16(Ah[1], Bl[n*2+1], cc, 0, 0, 0);
                cc = __builtin_amdgcn_mfma_f32_16x16x32_f16(Al[1], Bh[n*2+1], cc, 0, 0, 0);
                float pacc = 0.f;
                #pragma unroll
                for (int r = 0; r < 4; ++r) {
                    float v = hh[r] + cc[r] * (1.0f / 4096.0f) + b2n[n];
                    pacc = fmaf(ftanh(v), rt4[r], pacc);
                }
                if (n == 0) accg0 += pacc;
                else if (n == 1) accg1 += pacc;
                else if (n == 2) accg2 += pacc;
                else accg3 += pacc;
            }
        }
    }

    // cross-lane-group sum (over L>>4) and store
    #pragma unroll
    for (int n = 0; n < 4; ++n) {
        float v = (n == 0) ? accg0 : (n == 1) ? accg1 : (n == 2) ? accg2 : accg3;
        v += __shfl_xor(v, 16);
        v += __shfl_xor(v, 32);
        if (L < 16) agg[blk * 64 + n * 16 + L] = v * 0.0625f;
    }
}

// ---------------------------------------------------------------------------
// Node kernel: GRU + output MLP + pred write + next-step projections.
// ---------------------------------------------------------------------------
__global__ __launch_bounds__(64) void k_node(
    const float* __restrict__ aggraw, const float* __restrict__ cln,
    float* __restrict__ hbuf, float* __restrict__ xbuf,
    const float* __restrict__ irw, const float* __restrict__ irb,
    const float* __restrict__ izw, const float* __restrict__ izb,
    const float* __restrict__ inw, const float* __restrict__ inb,
    const float* __restrict__ hrw, const float* __restrict__ hrbv,
    const float* __restrict__ hnw, const float* __restrict__ hnbv,
    const float* __restrict__ o1w, const float* __restrict__ o1b,
    const float* __restrict__ o2w, const float* __restrict__ o2b,
    const float* __restrict__ o3w, const float* __restrict__ o3b,
    const float* __restrict__ w1, const float* __restrict__ b1,
    float* __restrict__ Hrb, float* __restrict__ Hs,
    float* __restrict__ out, int tout)
{
    int blk = blockIdx.x;
    int b = blk >> 6, n = blk & 63;
    int l = threadIdx.x;
    __shared__ float sA[64], sH[64], sP[64];

    float a = aggraw[blk * 64 + l] + cln[blk * 64 + l];
    sA[l] = a;
    float h_old = hbuf[blk * 64 + l];
    float x0 = xbuf[blk * 4 + 0], x1 = xbuf[blk * 4 + 1];
    float x2 = xbuf[blk * 4 + 2], x3 = xbuf[blk * 4 + 3];
    __syncthreads();

    float hra = hrbv[l], hna = hnbv[l];
    #pragma unroll 8
    for (int k = 0; k < 64; ++k) {
        float av = sA[k];
        hra = fmaf(av, hrw[k * 64 + l], hra);
        hna = fmaf(av, hnw[k * 64 + l], hna);
    }
    float xr = irb[l]; float xz = izb[l]; float xn = inb[l];
    xr = fmaf(x0, irw[l], xr); xr = fmaf(x1, irw[64 + l], xr);
    xr = fmaf(x2, irw[128 + l], xr); xr = fmaf(x3, irw[192 + l], xr);
    xz = fmaf(x0, izw[l], xz); xz = fmaf(x1, izw[64 + l], xz);
    xz = fmaf(x2, izw[128 + l], xz); xz = fmaf(x3, izw[192 + l], xz);
    xn = fmaf(x0, inw[l], xn); xn = fmaf(x1, inw[64 + l], xn);
    xn = fmaf(x2, inw[128 + l], xn); xn = fmaf(x3, inw[192 + l], xn);

    float r = fsig(xr + hra);
    float z = fsig(xz + hra);
    float nn = ftanh(xn + r * hna);
    float hnew = (1.f - z) * nn + z * h_old;
    hbuf[blk * 64 + l] = hnew;
    sH[l] = hnew;
    __syncthreads();

    float p = o1b[l];
    #pragma unroll 8
    for (int k = 0; k < 64; ++k) p = fmaf(sH[k], o1w[k * 64 + l], p);
    p = fmaxf(p, 0.f);
    sP[l] = p;
    __syncthreads();
    float q = o2b[l];
    #pragma unroll 8
    for (int k = 0; k < 64; ++k) q = fmaf(sP[k], o2w[k * 64 + l], q);
    q = fmaxf(q, 0.f);
    __syncthreads();
    sP[l] = q;
    __syncthreads();
    if (l < 4) {
        float xv = (l == 0) ? x0 : (l == 1) ? x1 : (l == 2) ? x2 : x3;
        float pr = xv + o3b[l];
        #pragma unroll 8
        for (int k = 0; k < 64; ++k) pr = fmaf(sP[k], o3w[k * 4 + l], pr);
        out[(blk * Tz + tout) * 4 + l] = pr;
        xbuf[blk * 4 + l] = pr;
    }

    #pragma unroll 1
    for (int t = 0; t < 4; ++t) {
        const float* w = w1 + t * 8192;
        float ar = b1[t * 64 + l], as = 0.f;
        #pragma unroll 8
        for (int c = 0; c < 64; ++c) {
            float hv = sH[c];
            ar = fmaf(hv, w[c * 64 + l], ar);
            as = fmaf(hv, w[(c + 64) * 64 + l], as);
        }
        Hrb[(blk * 4 + t) * 64 + l] = ar;
        Hs[((b * 4 + t) * 64 + l) * 64 + n] = as;
    }
}

// ---------------------------------------------------------------------------
extern "C" void kernel_launch(void* const* d_in, const int* in_sizes, int n_in,
                              void* d_out, int out_size, void* d_ws, size_t ws_size,
                              hipStream_t stream)
{
    const float* data     = (const float*)d_in[0];
    const float* rel_type = (const float*)d_in[1];
    const float* clinical = (const float*)d_in[4];
    const float* msg_w1 = (const float*)d_in[5];
    const float* msg_b1 = (const float*)d_in[6];
    const float* msg_w2 = (const float*)d_in[7];
    const float* msg_b2 = (const float*)d_in[8];
    const float* chw1 = (const float*)d_in[9];
    const float* chb1 = (const float*)d_in[10];
    const float* chw2 = (const float*)d_in[11];
    const float* chb2 = (const float*)d_in[12];
    const float* chw3 = (const float*)d_in[13];
    const float* chb3 = (const float*)d_in[14];
    const float* cmw1 = (const float*)d_in[15];
    const float* cmb1 = (const float*)d_in[16];
    const float* cmw2 = (const float*)d_in[17];
    const float* cmb2 = (const float*)d_in[18];
    const float* cmw3 = (const float*)d_in[19];
    const float* cmb3 = (const float*)d_in[20];
    const float* irw = (const float*)d_in[21];
    const float* irb = (const float*)d_in[22];
    const float* izw = (const float*)d_in[23];
    const float* izb = (const float*)d_in[24];
    const float* inw = (const float*)d_in[25];
    const float* inb = (const float*)d_in[26];
    const float* hrw = (const float*)d_in[27];
    const float* hrb = (const float*)d_in[28];
    const float* hnw = (const float*)d_in[29];
    const float* hnb = (const float*)d_in[30];
    const float* o1w = (const float*)d_in[31];
    const float* o1b = (const float*)d_in[32];
    const float* o2w = (const float*)d_in[33];
    const float* o2b = (const float*)d_in[34];
    const float* o3w = (const float*)d_in[35];
    const float* o3b = (const float*)d_in[36];

    float* ws   = (float*)d_ws;
    float* hbuf = ws;                 // B*N*H           = 262144
    float* cln  = ws + 262144;        // B*N*H           = 262144
    float* Hrb  = ws + 524288;        // B*N*ET*H        = 1048576
    float* Hs   = ws + 1572864;       // B*ET*H*N        = 1048576
    float* agg  = ws + 2621440;       // B*N*H           = 262144
    float* xbuf = ws + 2883584;       // B*N*D           = 16384
    u32*   Wf   = (u32*)(ws + 2899968); // ET*H*H        = 16384 u32
    float* out  = (float*)d_out;

    k_clinical<<<dim3(512), dim3(128), 0, stream>>>(
        clinical, chw1, chb1, chw2, chb2, chw3, chb3,
        cmw1, cmb1, cmw2, cmb2, cmw3, cmb3, hbuf, cln);
    k_wprep<<<dim3(64), dim3(256), 0, stream>>>(msg_w2, Wf);
    k_init<<<dim3(64), dim3(256), 0, stream>>>(data, xbuf, out);
    k_proj<<<dim3(Bz * Nz), dim3(64), 0, stream>>>(hbuf, msg_w1, msg_b1, Hrb, Hs);

    for (int t = 1; t < Tz; ++t) {
        k_edge<<<dim3(Bz * Nz), dim3(64), 0, stream>>>(Hrb, Hs, rel_type, msg_b2, Wf, agg);
        k_node<<<dim3(Bz * Nz), dim3(64), 0, stream>>>(
            agg, cln, hbuf, xbuf,
            irw, irb, izw, izb, inw, inb,
            hrw, hrb, hnw, hnb,
            o1w, o1b, o2w, o2b, o3w, o3b,
            msg_w1, msg_b1, Hrb, Hs, out, t);
    }
}